// Round 14
// baseline (589.879 us; speedup 1.0000x reference)
//
#include <hip/hip_runtime.h>
#include <stdint.h>
#include <stddef.h>

// ScaledDotProductAttention: B=64, Lq=Lk=2048, D=64, fp32 in/out.
// out tuple = (output [64][2048][64], attn [64][2048][2048]) concat in d_out.
// R14: R13 + occupancy push under the 170-VGPR step (3 waves/SIMD):
//  - K pipeline 8 -> 4 sets (Kf is XCD-L2-resident; 4-tile lookahead plenty)
//  - online max+sum folded into Phase A (A2 pass deleted; B recomputes
//    e = exp(s - mg) * rl directly — identical math)
//  - __launch_bounds__(256,3); fused K/V fragment pre-pass (one dispatch).

typedef __attribute__((ext_vector_type(4))) float f32x4;
typedef __fp16 f16x2 __attribute__((ext_vector_type(2)));
typedef __fp16 f16x4 __attribute__((ext_vector_type(4)));
typedef __fp16 f16x8 __attribute__((ext_vector_type(8)));

static constexpr int BATCH = 64;
static constexpr int SEQ   = 2048;
static constexpr int HD    = 64;
static constexpr float NEGH = -60000.0f;  // "-inf" that survives fp16

// ---------------- fused pre-pass: K and V -> fragment layouts fp16 --------
// blocks 0..2047: Kf[b][kt][half][l15*64+g*16] = K[b][kt*16+l15][half*32+g*8..+7]
// blocks 2048..4095: Vf[b][kt][db][l15*32+g*8] = V[b][kt*16+g*4+j][db*16+l15]
__global__ void frag_kernel(const float* __restrict__ k, const float* __restrict__ v,
                            __fp16* __restrict__ kf, __fp16* __restrict__ vf) {
  __shared__ float tile[64][68];
  if (blockIdx.x < 2048) {
    const int b    = blockIdx.x >> 5;
    const int ch   = blockIdx.x & 31;
    const int tid  = threadIdx.x;
    const int tl   = tid >> 6;
    const int lane = tid & 63;
    const int l15  = lane & 15;
    const int g    = lane >> 4;
    const int kt   = ch * 4 + tl;
    const float* src = k + ((size_t)(b * SEQ + kt * 16 + l15)) * HD + g * 8;
    char* dst = (char*)kf + ((size_t)(b * 128 + kt)) * 2048 + l15 * 64 + g * 16;
#pragma unroll
    for (int half = 0; half < 2; ++half) {
      f32x4 a = *(const f32x4*)(src + half * 32);
      f32x4 c = *(const f32x4*)(src + half * 32 + 4);
      f16x2 p0 = __builtin_amdgcn_cvt_pkrtz(a[0], a[1]);
      f16x2 p1 = __builtin_amdgcn_cvt_pkrtz(a[2], a[3]);
      f16x2 p2 = __builtin_amdgcn_cvt_pkrtz(c[0], c[1]);
      f16x2 p3 = __builtin_amdgcn_cvt_pkrtz(c[2], c[3]);
      f16x8 o;
      o[0] = p0[0]; o[1] = p0[1]; o[2] = p1[0]; o[3] = p1[1];
      o[4] = p2[0]; o[5] = p2[1]; o[6] = p3[0]; o[7] = p3[1];
      *(f16x8*)(dst + half * 1024) = o;
    }
  } else {
    const int bid = blockIdx.x - 2048;
    const int b   = bid >> 5;
    const int ch  = bid & 31;
    const int tid = threadIdx.x;
    const int kk  = tid >> 4;
    const int d4  = (tid & 15) << 2;
    const int k0  = ch * 64;
#pragma unroll
    for (int i = 0; i < 4; ++i) {
      f32x4 val = *(const f32x4*)(v + ((size_t)(b * SEQ + k0 + kk + 16 * i)) * HD + d4);
      tile[kk + 16 * i][d4 + 0] = val[0];
      tile[kk + 16 * i][d4 + 1] = val[1];
      tile[kk + 16 * i][d4 + 2] = val[2];
      tile[kk + 16 * i][d4 + 3] = val[3];
    }
    __syncthreads();
    const int tl  = tid >> 6;
    const int db  = (tid >> 4) & 3;
    const int l15 = tid & 15;
    f16x8 o0, o1;
#pragma unroll
    for (int g = 0; g < 2; ++g)
#pragma unroll
      for (int j = 0; j < 4; ++j)
        o0[g * 4 + j] = (__fp16)tile[tl * 16 + g * 4 + j][db * 16 + l15];
#pragma unroll
    for (int g = 0; g < 2; ++g)
#pragma unroll
      for (int j = 0; j < 4; ++j)
        o1[g * 4 + j] = (__fp16)tile[tl * 16 + (g + 2) * 4 + j][db * 16 + l15];
    char* dst = (char*)vf + ((size_t)(b * 128 + ch * 4 + tl)) * 2048 + db * 512 + l15 * 32;
    *(f16x8*)(dst)      = o0;
    *(f16x8*)(dst + 16) = o1;
  }
}

// ---------------- main fused attention ----------------
__global__ __launch_bounds__(256, 3) void attn_kernel(
    const float* __restrict__ q,
    const __fp16* __restrict__ kf,
    const __fp16* __restrict__ vf,
    const float* __restrict__ mask,
    float* __restrict__ out,
    float* __restrict__ attn) {
  __shared__ __align__(16) char pool[4][4352];  // per-wave mask/attn bounce; O-reduce alias
  __shared__ float stat_m[4][16];
  __shared__ float stat_l[4][16];

  const int tid  = threadIdx.x;
  const int w    = tid >> 6;
  const int lane = tid & 63;
  const int l15  = lane & 15;
  const int g    = lane >> 4;
  const int g4   = g << 2;

  // XCD remap: XCD x handles batches 8x..8x+7 exclusively (L2 residency)
  const int bid = blockIdx.x;
  const int xcd = bid & 7;
  const int r   = bid >> 3;
  const int b   = xcd * 8 + (r >> 7);
  const int q0  = (r & 127) << 4;
  const int wk0 = w << 9;

  char* wb = pool[w];
  const int koff = l15 * 64 + g * 16;
  const int voff = l15 * 32 + g * 8;

  const char* kfb = (const char*)kf + ((size_t)(b * 128) + w * 32) * 2048;
  const char* vfb = (const char*)vf + ((size_t)(b * 128) + w * 32) * 2048;
  const float* mbase = mask + ((size_t)(b * SEQ + q0)) * SEQ + wk0;
  float*       abase = attn + ((size_t)(b * SEQ + q0)) * SEQ + wk0;

  // Q fp32 -> fp16 fragments in-kernel (col=l15 -> q-row, k=g*8+j -> d)
  f16x8 qb0, qb1;
  {
    const float* qsrc = q + ((size_t)(b * SEQ + q0 + l15)) * HD + g * 8;
    f32x4 a0 = *(const f32x4*)(qsrc);
    f32x4 a1 = *(const f32x4*)(qsrc + 4);
    f32x4 c0 = *(const f32x4*)(qsrc + 32);
    f32x4 c1 = *(const f32x4*)(qsrc + 36);
    f16x2 p0 = __builtin_amdgcn_cvt_pkrtz(a0[0], a0[1]);
    f16x2 p1 = __builtin_amdgcn_cvt_pkrtz(a0[2], a0[3]);
    f16x2 p2 = __builtin_amdgcn_cvt_pkrtz(a1[0], a1[1]);
    f16x2 p3 = __builtin_amdgcn_cvt_pkrtz(a1[2], a1[3]);
    qb0[0] = p0[0]; qb0[1] = p0[1]; qb0[2] = p1[0]; qb0[3] = p1[1];
    qb0[4] = p2[0]; qb0[5] = p2[1]; qb0[6] = p3[0]; qb0[7] = p3[1];
    p0 = __builtin_amdgcn_cvt_pkrtz(c0[0], c0[1]);
    p1 = __builtin_amdgcn_cvt_pkrtz(c0[2], c0[3]);
    p2 = __builtin_amdgcn_cvt_pkrtz(c1[0], c1[1]);
    p3 = __builtin_amdgcn_cvt_pkrtz(c1[2], c1[3]);
    qb1[0] = p0[0]; qb1[1] = p0[1]; qb1[2] = p1[0]; qb1[3] = p1[1];
    qb1[4] = p2[0]; qb1[5] = p2[1]; qb1[6] = p3[0]; qb1[7] = p3[1];
  }

  // 32 named logit fragments (store s; e recomputed in Phase B)
  f16x4 PH0,  PH1,  PH2,  PH3,  PH4,  PH5,  PH6,  PH7;
  f16x4 PH8,  PH9,  PH10, PH11, PH12, PH13, PH14, PH15;
  f16x4 PH16, PH17, PH18, PH19, PH20, PH21, PH22, PH23;
  f16x4 PH24, PH25, PH26, PH27, PH28, PH29, PH30, PH31;

  // K pipeline: 4 named sets (4-tile lookahead; Kf is L2-resident)
  f16x8 K0A, K0B, K1A, K1B, K2A, K2B, K3A, K3B;
  // mask pipeline: 2 group sets (8-tile lookahead, HBM)
  f32x4 MA0, MA1, MA2, MA3;
  f32x4 MB0, MB1, MB2, MB3;
  float m = -3.0e38f;   // running per-lane max (over this lane's 128 k's)
  float l = 0.f;        // running per-lane sum of exp(s - m)

#define ISSUE_K(t, KA, KB)                                                   \
  KA = *(const f16x8*)(kfb + (size_t)(t) * 2048 + koff);                     \
  KB = *(const f16x8*)(kfb + (size_t)(t) * 2048 + 1024 + koff);

#define ISSUE_M(c, M0, M1, M2, M3)                                           \
  M0 = __builtin_nontemporal_load((const f32x4*)(mbase + (size_t)(0 * 4 + g) * SEQ + (c) * 64 + l15 * 4)); \
  M1 = __builtin_nontemporal_load((const f32x4*)(mbase + (size_t)(1 * 4 + g) * SEQ + (c) * 64 + l15 * 4)); \
  M2 = __builtin_nontemporal_load((const f32x4*)(mbase + (size_t)(2 * 4 + g) * SEQ + (c) * 64 + l15 * 4)); \
  M3 = __builtin_nontemporal_load((const f32x4*)(mbase + (size_t)(3 * 4 + g) * SEQ + (c) * 64 + l15 * 4));

#define WRITE_M(M0, M1, M2, M3)                                              \
  *(f32x4*)(wb + (0 * 4 + g) * 272 + l15 * 16) = M0;                         \
  *(f32x4*)(wb + (1 * 4 + g) * 272 + l15 * 16) = M1;                         \
  *(f32x4*)(wb + (2 * 4 + g) * 272 + l15 * 16) = M2;                         \
  *(f32x4*)(wb + (3 * 4 + g) * 272 + l15 * 16) = M3;

#define ATILE(t, PH, KA, KB)                                                 \
  {                                                                          \
    f32x4 acc = {0.f, 0.f, 0.f, 0.f};                                        \
    acc = __builtin_amdgcn_mfma_f32_16x16x32_f16(KA, qb0, acc, 0, 0, 0);     \
    acc = __builtin_amdgcn_mfma_f32_16x16x32_f16(KB, qb1, acc, 0, 0, 0);     \
    const f32x4 mv = *(const f32x4*)(wb + l15 * 272 + ((t) & 3) * 64 + g * 16); \
    float s0 = (mv[0] < 0.f) ? NEGH : fmaf(acc[0], 0.125f, mv[0]);           \
    float s1 = (mv[1] < 0.f) ? NEGH : fmaf(acc[1], 0.125f, mv[1]);           \
    float s2 = (mv[2] < 0.f) ? NEGH : fmaf(acc[2], 0.125f, mv[2]);           \
    float s3 = (mv[3] < 0.f) ? NEGH : fmaf(acc[3], 0.125f, mv[3]);           \
    const float tm = fmaxf(fmaxf(s0, s1), fmaxf(s2, s3));                    \
    const float nm = fmaxf(m, tm);                                           \
    l = l * __expf(m - nm) + __expf(s0 - nm) + __expf(s1 - nm)               \
        + __expf(s2 - nm) + __expf(s3 - nm);                                 \
    m = nm;                                                                  \
    f16x2 lo_ = __builtin_amdgcn_cvt_pkrtz(s0, s1);                          \
    f16x2 hi_ = __builtin_amdgcn_cvt_pkrtz(s2, s3);                          \
    PH = (f16x4){lo_[0], lo_[1], hi_[0], hi_[1]};                            \
  }

#define AT(t, PH, KA, KB)  ATILE(t, PH, KA, KB) ISSUE_K((t) + 4, KA, KB)
#define ATL(t, PH, KA, KB) ATILE(t, PH, KA, KB)

  // ---- Phase A prologue: strict need-order issue ----
  ISSUE_M(0, MA0, MA1, MA2, MA3)
  ISSUE_K(0, K0A, K0B) ISSUE_K(1, K1A, K1B) ISSUE_K(2, K2A, K2B) ISSUE_K(3, K3A, K3B)
  ISSUE_M(1, MB0, MB1, MB2, MB3)

  WRITE_M(MA0, MA1, MA2, MA3) ISSUE_M(2, MA0, MA1, MA2, MA3)
  AT(0, PH0, K0A, K0B)  AT(1, PH1, K1A, K1B)  AT(2, PH2, K2A, K2B)  AT(3, PH3, K3A, K3B)
  WRITE_M(MB0, MB1, MB2, MB3) ISSUE_M(3, MB0, MB1, MB2, MB3)
  AT(4, PH4, K0A, K0B)  AT(5, PH5, K1A, K1B)  AT(6, PH6, K2A, K2B)  AT(7, PH7, K3A, K3B)
  WRITE_M(MA0, MA1, MA2, MA3) ISSUE_M(4, MA0, MA1, MA2, MA3)
  AT(8, PH8, K0A, K0B)  AT(9, PH9, K1A, K1B)  AT(10, PH10, K2A, K2B) AT(11, PH11, K3A, K3B)
  WRITE_M(MB0, MB1, MB2, MB3) ISSUE_M(5, MB0, MB1, MB2, MB3)
  AT(12, PH12, K0A, K0B) AT(13, PH13, K1A, K1B) AT(14, PH14, K2A, K2B) AT(15, PH15, K3A, K3B)
  WRITE_M(MA0, MA1, MA2, MA3) ISSUE_M(6, MA0, MA1, MA2, MA3)
  AT(16, PH16, K0A, K0B) AT(17, PH17, K1A, K1B) AT(18, PH18, K2A, K2B) AT(19, PH19, K3A, K3B)
  WRITE_M(MB0, MB1, MB2, MB3) ISSUE_M(7, MB0, MB1, MB2, MB3)
  AT(20, PH20, K0A, K0B) AT(21, PH21, K1A, K1B) AT(22, PH22, K2A, K2B) AT(23, PH23, K3A, K3B)
  WRITE_M(MA0, MA1, MA2, MA3)
  AT(24, PH24, K0A, K0B) AT(25, PH25, K1A, K1B) AT(26, PH26, K2A, K2B) AT(27, PH27, K3A, K3B)
  WRITE_M(MB0, MB1, MB2, MB3)
  ATL(28, PH28, K0A, K0B) ATL(29, PH29, K1A, K1B) ATL(30, PH30, K2A, K2B) ATL(31, PH31, K3A, K3B)

#undef AT
#undef ATL
#undef ATILE
#undef ISSUE_K
#undef ISSUE_M
#undef WRITE_M

  // ---- cross-lane reduce (4 g-groups share q-row l15) ----
  {
    float mw = fmaxf(m, __shfl_xor(m, 16));
    mw = fmaxf(mw, __shfl_xor(mw, 32));
    float lad = l * __expf(m - mw);
    lad += __shfl_xor(lad, 16);
    lad += __shfl_xor(lad, 32);
    if (lane < 16) { stat_m[w][lane] = mw; stat_l[w][lane] = lad; }
  }
  __syncthreads();

  float mg = -3.0e38f;
#pragma unroll
  for (int ww = 0; ww < 4; ++ww) mg = fmaxf(mg, stat_m[ww][l15]);
  float lg = 0.f;
#pragma unroll
  for (int ww = 0; ww < 4; ++ww) lg += stat_l[ww][l15] * __expf(stat_m[ww][l15] - mg);
  const float rl = 1.0f / lg;

  // ---- Phase B: e = exp(s - mg) * rl; attn via LDS bounce; PV MFMA ----
  f32x4 oacc0 = {0.f, 0.f, 0.f, 0.f};
  f32x4 oacc1 = {0.f, 0.f, 0.f, 0.f};
  f32x4 oacc2 = {0.f, 0.f, 0.f, 0.f};
  f32x4 oacc3 = {0.f, 0.f, 0.f, 0.f};

  // V pipeline: 4 named sets x 4 db blocks
  f16x4 V0a, V0b, V0c, V0d, V1a, V1b, V1c, V1d;
  f16x4 V2a, V2b, V2c, V2d, V3a, V3b, V3c, V3d;

#define ISSUE_V(t, Va, Vb, Vc, Vd)                                           \
  Va = *(const f16x4*)(vfb + (size_t)(t) * 2048 + 0 * 512 + voff);           \
  Vb = *(const f16x4*)(vfb + (size_t)(t) * 2048 + 1 * 512 + voff);           \
  Vc = *(const f16x4*)(vfb + (size_t)(t) * 2048 + 2 * 512 + voff);           \
  Vd = *(const f16x4*)(vfb + (size_t)(t) * 2048 + 3 * 512 + voff);

#define BTILE(t, PH, Va, Vb, Vc, Vd)                                         \
  {                                                                          \
    float e0 = __expf((float)PH[0] - mg) * rl;                               \
    float e1 = __expf((float)PH[1] - mg) * rl;                               \
    float e2 = __expf((float)PH[2] - mg) * rl;                               \
    float e3 = __expf((float)PH[3] - mg) * rl;                               \
    f32x4 st;                                                                \
    st[0] = e0; st[1] = e1; st[2] = e2; st[3] = e3;                          \
    *(f32x4*)(wb + l15 * 272 + ((t) & 3) * 64 + g * 16) = st;                \
    f16x2 lo_ = __builtin_amdgcn_cvt_pkrtz(e0, e1);                          \
    f16x2 hi_ = __builtin_amdgcn_cvt_pkrtz(e2, e3);                          \
    const f16x4 pf = (f16x4){lo_[0], lo_[1], hi_[0], hi_[1]};                \
    oacc0 = __builtin_amdgcn_mfma_f32_16x16x16f16(Va, pf, oacc0, 0, 0, 0);   \
    oacc1 = __builtin_amdgcn_mfma_f32_16x16x16f16(Vb, pf, oacc1, 0, 0, 0);   \
    oacc2 = __builtin_amdgcn_mfma_f32_16x16x16f16(Vc, pf, oacc2, 0, 0, 0);   \
    oacc3 = __builtin_amdgcn_mfma_f32_16x16x16f16(Vd, pf, oacc3, 0, 0, 0);   \
  }

#define STORE_A(c)                                                           \
  __builtin_nontemporal_store(                                               \
      *(const f32x4*)(wb + (0 * 4 + g) * 272 + l15 * 16),                    \
      (f32x4*)(abase + (size_t)(0 * 4 + g) * SEQ + (c) * 64 + l15 * 4));     \
  __builtin_nontemporal_store(                                               \
      *(const f32x4*)(wb + (1 * 4 + g) * 272 + l15 * 16),                    \
      (f32x4*)(abase + (size_t)(1 * 4 + g) * SEQ + (c) * 64 + l15 * 4));     \
  __builtin_nontemporal_store(                                               \
      *(const f32x4*)(wb + (2 * 4 + g) * 272 + l15 * 16),                    \
      (f32x4*)(abase + (size_t)(2 * 4 + g) * SEQ + (c) * 64 + l15 * 4));     \
  __builtin_nontemporal_store(                                               \
      *(const f32x4*)(wb + (3 * 4 + g) * 272 + l15 * 16),                    \
      (f32x4*)(abase + (size_t)(3 * 4 + g) * SEQ + (c) * 64 + l15 * 4));

#define BS(t, PH, Va, Vb, Vc, Vd)  BTILE(t, PH, Va, Vb, Vc, Vd) ISSUE_V((t) + 4, Va, Vb, Vc, Vd)
#define BSL(t, PH, Va, Vb, Vc, Vd) BTILE(t, PH, Va, Vb, Vc, Vd)

  ISSUE_V(0, V0a, V0b, V0c, V0d) ISSUE_V(1, V1a, V1b, V1c, V1d)
  ISSUE_V(2, V2a, V2b, V2c, V2d) ISSUE_V(3, V3a, V3b, V3c, V3d)

  BS(0, PH0, V0a, V0b, V0c, V0d)   BS(1, PH1, V1a, V1b, V1c, V1d)
  BS(2, PH2, V2a, V2b, V2c, V2d)   BS(3, PH3, V3a, V3b, V3c, V3d)   STORE_A(0)
  BS(4, PH4, V0a, V0b, V0c, V0d)   BS(5, PH5, V1a, V1b, V1c, V1d)
  BS(6, PH6, V2a, V2b, V2c, V2d)   BS(7, PH7, V3a, V3b, V3c, V3d)   STORE_A(1)
  BS(8, PH8, V0a, V0b, V0c, V0d)   BS(9, PH9, V1a, V1b, V1c, V1d)
  BS(10, PH10, V2a, V2b, V2c, V2d) BS(11, PH11, V3a, V3b, V3c, V3d) STORE_A(2)
  BS(12, PH12, V0a, V0b, V0c, V0d) BS(13, PH13, V1a, V1b, V1c, V1d)
  BS(14, PH14, V2a, V2b, V2c, V2d) BS(15, PH15, V3a, V3b, V3c, V3d) STORE_A(3)
  BS(16, PH16, V0a, V0b, V0c, V0d) BS(17, PH17, V1a, V1b, V1c, V1d)
  BS(18, PH18, V2a, V2b, V2c, V2d) BS(19, PH19, V3a, V3b, V3c, V3d) STORE_A(4)
  BS(20, PH20, V0a, V0b, V0c, V0d) BS(21, PH21, V1a, V1b, V1c, V1d)
  BS(22, PH22, V2a, V2b, V2c, V2d) BS(23, PH23, V3a, V3b, V3c, V3d) STORE_A(5)
  BS(24, PH24, V0a, V0b, V0c, V0d) BS(25, PH25, V1a, V1b, V1c, V1d)
  BS(26, PH26, V2a, V2b, V2c, V2d) BS(27, PH27, V3a, V3b, V3c, V3d) STORE_A(6)
  BSL(28, PH28, V0a, V0b, V0c, V0d) BSL(29, PH29, V1a, V1b, V1c, V1d)
  BSL(30, PH30, V2a, V2b, V2c, V2d) BSL(31, PH31, V3a, V3b, V3c, V3d) STORE_A(7)

#undef BS
#undef BSL
#undef BTILE
#undef ISSUE_V
#undef STORE_A

  // ---- cross-wave partial-O reduction (aliases the per-wave bounce buf) ----
  float* sred_w = (float*)pool[w];   // 1088 floats = 4352 B exactly
#pragma unroll
  for (int rr = 0; rr < 4; ++rr) {
    sred_w[(0 * 16 + g4 + rr) * 17 + l15] = oacc0[rr];
    sred_w[(1 * 16 + g4 + rr) * 17 + l15] = oacc1[rr];
    sred_w[(2 * 16 + g4 + rr) * 17 + l15] = oacc2[rr];
    sred_w[(3 * 16 + g4 + rr) * 17 + l15] = oacc3[rr];
  }
  __syncthreads();

#pragma unroll
  for (int ii = 0; ii < 4; ++ii) {
    const int i = tid + ii * 256;     // i in [0,1024): qq = i>>6, d = i&63
    const int qq = i >> 6;
    const int d = i & 63;
    const int o = d * 17 + qq;
    float s = ((const float*)pool[0])[o] + ((const float*)pool[1])[o] +
              ((const float*)pool[2])[o] + ((const float*)pool[3])[o];
    out[((size_t)(b * SEQ + q0 + qq)) * HD + d] = s;
  }
}

extern "C" void kernel_launch(void* const* d_in, const int* in_sizes, int n_in,
                              void* d_out, int out_size, void* d_ws, size_t ws_size,
                              hipStream_t stream) {
  const float* q    = (const float*)d_in[0];
  const float* k    = (const float*)d_in[1];
  const float* v    = (const float*)d_in[2];
  const float* mask = (const float*)d_in[3];

  float* out  = (float*)d_out;
  float* attn = out + (size_t)BATCH * SEQ * HD;  // tuple: (output, attn)

  const size_t nqk = (size_t)BATCH * SEQ * HD;
  __fp16* kfrag = (__fp16*)d_ws;
  __fp16* vfrag = kfrag + nqk;

  frag_kernel<<<dim3(2 * BATCH * 32), dim3(256), 0, stream>>>(k, v, kfrag, vfrag);
  attn_kernel<<<dim3(BATCH * (SEQ / 16)), dim3(256), 0, stream>>>(q, kfrag, vfrag, mask, out, attn);
}

// Round 15
// 518.488 us; speedup vs baseline: 1.1377x; 1.1377x over previous
//
#include <hip/hip_runtime.h>
#include <stdint.h>
#include <stddef.h>

// ScaledDotProductAttention: B=64, Lq=Lk=2048, D=64, fp32 in/out.
// out tuple = (output [64][2048][64], attn [64][2048][2048]) concat in d_out.
// R15: R13 structure exactly (separate A2 softmax pass, e stored fp16) with
// ONLY the occupancy change isolated from R14: K pipeline 8->4 register sets
// (Kf is XCD-L2-resident, ~250cy; 4-tile lookahead covers it) and
// __launch_bounds__(256,3) for 3 waves/SIMD. Fused fragment pre-pass kept.

typedef __attribute__((ext_vector_type(4))) float f32x4;
typedef __fp16 f16x2 __attribute__((ext_vector_type(2)));
typedef __fp16 f16x4 __attribute__((ext_vector_type(4)));
typedef __fp16 f16x8 __attribute__((ext_vector_type(8)));

static constexpr int BATCH = 64;
static constexpr int SEQ   = 2048;
static constexpr int HD    = 64;
static constexpr float NEGH = -60000.0f;  // "-inf" that survives fp16

// ---------------- fused pre-pass: K and V -> fragment layouts fp16 --------
__global__ void frag_kernel(const float* __restrict__ k, const float* __restrict__ v,
                            __fp16* __restrict__ kf, __fp16* __restrict__ vf) {
  __shared__ float tile[64][68];
  if (blockIdx.x < 2048) {
    const int b    = blockIdx.x >> 5;
    const int ch   = blockIdx.x & 31;
    const int tid  = threadIdx.x;
    const int tl   = tid >> 6;
    const int lane = tid & 63;
    const int l15  = lane & 15;
    const int g    = lane >> 4;
    const int kt   = ch * 4 + tl;
    const float* src = k + ((size_t)(b * SEQ + kt * 16 + l15)) * HD + g * 8;
    char* dst = (char*)kf + ((size_t)(b * 128 + kt)) * 2048 + l15 * 64 + g * 16;
#pragma unroll
    for (int half = 0; half < 2; ++half) {
      f32x4 a = *(const f32x4*)(src + half * 32);
      f32x4 c = *(const f32x4*)(src + half * 32 + 4);
      f16x2 p0 = __builtin_amdgcn_cvt_pkrtz(a[0], a[1]);
      f16x2 p1 = __builtin_amdgcn_cvt_pkrtz(a[2], a[3]);
      f16x2 p2 = __builtin_amdgcn_cvt_pkrtz(c[0], c[1]);
      f16x2 p3 = __builtin_amdgcn_cvt_pkrtz(c[2], c[3]);
      f16x8 o;
      o[0] = p0[0]; o[1] = p0[1]; o[2] = p1[0]; o[3] = p1[1];
      o[4] = p2[0]; o[5] = p2[1]; o[6] = p3[0]; o[7] = p3[1];
      *(f16x8*)(dst + half * 1024) = o;
    }
  } else {
    const int bid = blockIdx.x - 2048;
    const int b   = bid >> 5;
    const int ch  = bid & 31;
    const int tid = threadIdx.x;
    const int kk  = tid >> 4;
    const int d4  = (tid & 15) << 2;
    const int k0  = ch * 64;
#pragma unroll
    for (int i = 0; i < 4; ++i) {
      f32x4 val = *(const f32x4*)(v + ((size_t)(b * SEQ + k0 + kk + 16 * i)) * HD + d4);
      tile[kk + 16 * i][d4 + 0] = val[0];
      tile[kk + 16 * i][d4 + 1] = val[1];
      tile[kk + 16 * i][d4 + 2] = val[2];
      tile[kk + 16 * i][d4 + 3] = val[3];
    }
    __syncthreads();
    const int tl  = tid >> 6;
    const int db  = (tid >> 4) & 3;
    const int l15 = tid & 15;
    f16x8 o0, o1;
#pragma unroll
    for (int g = 0; g < 2; ++g)
#pragma unroll
      for (int j = 0; j < 4; ++j)
        o0[g * 4 + j] = (__fp16)tile[tl * 16 + g * 4 + j][db * 16 + l15];
#pragma unroll
    for (int g = 0; g < 2; ++g)
#pragma unroll
      for (int j = 0; j < 4; ++j)
        o1[g * 4 + j] = (__fp16)tile[tl * 16 + (g + 2) * 4 + j][db * 16 + l15];
    char* dst = (char*)vf + ((size_t)(b * 128 + ch * 4 + tl)) * 2048 + db * 512 + l15 * 32;
    *(f16x8*)(dst)      = o0;
    *(f16x8*)(dst + 16) = o1;
  }
}

// ---------------- main fused attention ----------------
__global__ __launch_bounds__(256, 3) void attn_kernel(
    const float* __restrict__ q,
    const __fp16* __restrict__ kf,
    const __fp16* __restrict__ vf,
    const float* __restrict__ mask,
    float* __restrict__ out,
    float* __restrict__ attn) {
  __shared__ __align__(16) char pool[4][4352];  // per-wave mask/attn bounce; O-reduce alias
  __shared__ float stat_m[4][16];
  __shared__ float stat_l[4][16];

  const int tid  = threadIdx.x;
  const int w    = tid >> 6;
  const int lane = tid & 63;
  const int l15  = lane & 15;
  const int g    = lane >> 4;
  const int g4   = g << 2;

  // XCD remap: XCD x handles batches 8x..8x+7 exclusively (L2 residency)
  const int bid = blockIdx.x;
  const int xcd = bid & 7;
  const int r   = bid >> 3;
  const int b   = xcd * 8 + (r >> 7);
  const int q0  = (r & 127) << 4;
  const int wk0 = w << 9;

  char* wb = pool[w];
  const int koff = l15 * 64 + g * 16;
  const int voff = l15 * 32 + g * 8;

  const char* kfb = (const char*)kf + ((size_t)(b * 128) + w * 32) * 2048;
  const char* vfb = (const char*)vf + ((size_t)(b * 128) + w * 32) * 2048;
  const float* mbase = mask + ((size_t)(b * SEQ + q0)) * SEQ + wk0;
  float*       abase = attn + ((size_t)(b * SEQ + q0)) * SEQ + wk0;

  // Q fp32 -> fp16 fragments in-kernel (col=l15 -> q-row, k=g*8+j -> d)
  f16x8 qb0, qb1;
  {
    const float* qsrc = q + ((size_t)(b * SEQ + q0 + l15)) * HD + g * 8;
    f32x4 a0 = *(const f32x4*)(qsrc);
    f32x4 a1 = *(const f32x4*)(qsrc + 4);
    f32x4 c0 = *(const f32x4*)(qsrc + 32);
    f32x4 c1 = *(const f32x4*)(qsrc + 36);
    f16x2 p0 = __builtin_amdgcn_cvt_pkrtz(a0[0], a0[1]);
    f16x2 p1 = __builtin_amdgcn_cvt_pkrtz(a0[2], a0[3]);
    f16x2 p2 = __builtin_amdgcn_cvt_pkrtz(a1[0], a1[1]);
    f16x2 p3 = __builtin_amdgcn_cvt_pkrtz(a1[2], a1[3]);
    qb0[0] = p0[0]; qb0[1] = p0[1]; qb0[2] = p1[0]; qb0[3] = p1[1];
    qb0[4] = p2[0]; qb0[5] = p2[1]; qb0[6] = p3[0]; qb0[7] = p3[1];
    p0 = __builtin_amdgcn_cvt_pkrtz(c0[0], c0[1]);
    p1 = __builtin_amdgcn_cvt_pkrtz(c0[2], c0[3]);
    p2 = __builtin_amdgcn_cvt_pkrtz(c1[0], c1[1]);
    p3 = __builtin_amdgcn_cvt_pkrtz(c1[2], c1[3]);
    qb1[0] = p0[0]; qb1[1] = p0[1]; qb1[2] = p1[0]; qb1[3] = p1[1];
    qb1[4] = p2[0]; qb1[5] = p2[1]; qb1[6] = p3[0]; qb1[7] = p3[1];
  }

  // 32 named logit fragments
  f16x4 PH0,  PH1,  PH2,  PH3,  PH4,  PH5,  PH6,  PH7;
  f16x4 PH8,  PH9,  PH10, PH11, PH12, PH13, PH14, PH15;
  f16x4 PH16, PH17, PH18, PH19, PH20, PH21, PH22, PH23;
  f16x4 PH24, PH25, PH26, PH27, PH28, PH29, PH30, PH31;

  // K pipeline: 4 named sets (4-tile lookahead; Kf is XCD-L2-resident)
  f16x8 K0A, K0B, K1A, K1B, K2A, K2B, K3A, K3B;
  // mask pipeline: 2 group sets (8-tile lookahead, HBM)
  f32x4 MA0, MA1, MA2, MA3;
  f32x4 MB0, MB1, MB2, MB3;
  float m = -3.0e38f;

#define ISSUE_K(t, KA, KB)                                                   \
  KA = *(const f16x8*)(kfb + (size_t)(t) * 2048 + koff);                     \
  KB = *(const f16x8*)(kfb + (size_t)(t) * 2048 + 1024 + koff);

#define ISSUE_M(c, M0, M1, M2, M3)                                           \
  M0 = __builtin_nontemporal_load((const f32x4*)(mbase + (size_t)(0 * 4 + g) * SEQ + (c) * 64 + l15 * 4)); \
  M1 = __builtin_nontemporal_load((const f32x4*)(mbase + (size_t)(1 * 4 + g) * SEQ + (c) * 64 + l15 * 4)); \
  M2 = __builtin_nontemporal_load((const f32x4*)(mbase + (size_t)(2 * 4 + g) * SEQ + (c) * 64 + l15 * 4)); \
  M3 = __builtin_nontemporal_load((const f32x4*)(mbase + (size_t)(3 * 4 + g) * SEQ + (c) * 64 + l15 * 4));

#define WRITE_M(M0, M1, M2, M3)                                              \
  *(f32x4*)(wb + (0 * 4 + g) * 272 + l15 * 16) = M0;                         \
  *(f32x4*)(wb + (1 * 4 + g) * 272 + l15 * 16) = M1;                         \
  *(f32x4*)(wb + (2 * 4 + g) * 272 + l15 * 16) = M2;                         \
  *(f32x4*)(wb + (3 * 4 + g) * 272 + l15 * 16) = M3;

#define ATILE(t, PH, KA, KB)                                                 \
  {                                                                          \
    f32x4 acc = {0.f, 0.f, 0.f, 0.f};                                        \
    acc = __builtin_amdgcn_mfma_f32_16x16x32_f16(KA, qb0, acc, 0, 0, 0);     \
    acc = __builtin_amdgcn_mfma_f32_16x16x32_f16(KB, qb1, acc, 0, 0, 0);     \
    const f32x4 mv = *(const f32x4*)(wb + l15 * 272 + ((t) & 3) * 64 + g * 16); \
    float s0 = (mv[0] < 0.f) ? NEGH : fmaf(acc[0], 0.125f, mv[0]);           \
    float s1 = (mv[1] < 0.f) ? NEGH : fmaf(acc[1], 0.125f, mv[1]);           \
    float s2 = (mv[2] < 0.f) ? NEGH : fmaf(acc[2], 0.125f, mv[2]);           \
    float s3 = (mv[3] < 0.f) ? NEGH : fmaf(acc[3], 0.125f, mv[3]);           \
    m = fmaxf(m, fmaxf(fmaxf(s0, s1), fmaxf(s2, s3)));                       \
    f16x2 lo_ = __builtin_amdgcn_cvt_pkrtz(s0, s1);                          \
    f16x2 hi_ = __builtin_amdgcn_cvt_pkrtz(s2, s3);                          \
    PH = (f16x4){lo_[0], lo_[1], hi_[0], hi_[1]};                            \
  }

#define AT(t, PH, KA, KB)  ATILE(t, PH, KA, KB) ISSUE_K((t) + 4, KA, KB)
#define ATL(t, PH, KA, KB) ATILE(t, PH, KA, KB)

  // ---- Phase A prologue: strict need-order issue ----
  ISSUE_M(0, MA0, MA1, MA2, MA3)
  ISSUE_K(0, K0A, K0B) ISSUE_K(1, K1A, K1B) ISSUE_K(2, K2A, K2B) ISSUE_K(3, K3A, K3B)
  ISSUE_M(1, MB0, MB1, MB2, MB3)

  WRITE_M(MA0, MA1, MA2, MA3) ISSUE_M(2, MA0, MA1, MA2, MA3)
  AT(0, PH0, K0A, K0B)  AT(1, PH1, K1A, K1B)  AT(2, PH2, K2A, K2B)  AT(3, PH3, K3A, K3B)
  WRITE_M(MB0, MB1, MB2, MB3) ISSUE_M(3, MB0, MB1, MB2, MB3)
  AT(4, PH4, K0A, K0B)  AT(5, PH5, K1A, K1B)  AT(6, PH6, K2A, K2B)  AT(7, PH7, K3A, K3B)
  WRITE_M(MA0, MA1, MA2, MA3) ISSUE_M(4, MA0, MA1, MA2, MA3)
  AT(8, PH8, K0A, K0B)  AT(9, PH9, K1A, K1B)  AT(10, PH10, K2A, K2B) AT(11, PH11, K3A, K3B)
  WRITE_M(MB0, MB1, MB2, MB3) ISSUE_M(5, MB0, MB1, MB2, MB3)
  AT(12, PH12, K0A, K0B) AT(13, PH13, K1A, K1B) AT(14, PH14, K2A, K2B) AT(15, PH15, K3A, K3B)
  WRITE_M(MA0, MA1, MA2, MA3) ISSUE_M(6, MA0, MA1, MA2, MA3)
  AT(16, PH16, K0A, K0B) AT(17, PH17, K1A, K1B) AT(18, PH18, K2A, K2B) AT(19, PH19, K3A, K3B)
  WRITE_M(MB0, MB1, MB2, MB3) ISSUE_M(7, MB0, MB1, MB2, MB3)
  AT(20, PH20, K0A, K0B) AT(21, PH21, K1A, K1B) AT(22, PH22, K2A, K2B) AT(23, PH23, K3A, K3B)
  WRITE_M(MA0, MA1, MA2, MA3)
  AT(24, PH24, K0A, K0B) AT(25, PH25, K1A, K1B) AT(26, PH26, K2A, K2B) AT(27, PH27, K3A, K3B)
  WRITE_M(MB0, MB1, MB2, MB3)
  ATL(28, PH28, K0A, K0B) ATL(29, PH29, K1A, K1B) ATL(30, PH30, K2A, K2B) ATL(31, PH31, K3A, K3B)

#undef AT
#undef ATL
#undef ATILE
#undef ISSUE_K
#undef ISSUE_M
#undef WRITE_M

  // row max across the 4 g-groups holding the same q-row
  m = fmaxf(m, __shfl_xor(m, 16));
  m = fmaxf(m, __shfl_xor(m, 32));

  // ---- Phase A2: e = exp(s - m), sum, repack e over s ----
  float lw = 0.f;
#define A2_STEP(PH)                                                          \
  {                                                                          \
    float e0 = __expf((float)PH[0] - m);                                     \
    float e1 = __expf((float)PH[1] - m);                                     \
    float e2 = __expf((float)PH[2] - m);                                     \
    float e3 = __expf((float)PH[3] - m);                                     \
    lw += (e0 + e1) + (e2 + e3);                                             \
    f16x2 lo_ = __builtin_amdgcn_cvt_pkrtz(e0, e1);                          \
    f16x2 hi_ = __builtin_amdgcn_cvt_pkrtz(e2, e3);                          \
    PH = (f16x4){lo_[0], lo_[1], hi_[0], hi_[1]};                            \
  }
  A2_STEP(PH0)  A2_STEP(PH1)  A2_STEP(PH2)  A2_STEP(PH3)
  A2_STEP(PH4)  A2_STEP(PH5)  A2_STEP(PH6)  A2_STEP(PH7)
  A2_STEP(PH8)  A2_STEP(PH9)  A2_STEP(PH10) A2_STEP(PH11)
  A2_STEP(PH12) A2_STEP(PH13) A2_STEP(PH14) A2_STEP(PH15)
  A2_STEP(PH16) A2_STEP(PH17) A2_STEP(PH18) A2_STEP(PH19)
  A2_STEP(PH20) A2_STEP(PH21) A2_STEP(PH22) A2_STEP(PH23)
  A2_STEP(PH24) A2_STEP(PH25) A2_STEP(PH26) A2_STEP(PH27)
  A2_STEP(PH28) A2_STEP(PH29) A2_STEP(PH30) A2_STEP(PH31)
#undef A2_STEP

  lw += __shfl_xor(lw, 16);
  lw += __shfl_xor(lw, 32);

  if (lane < 16) { stat_m[w][lane] = m; stat_l[w][lane] = lw; }
  __syncthreads();

  float mg = -3.0e38f;
#pragma unroll
  for (int ww = 0; ww < 4; ++ww) mg = fmaxf(mg, stat_m[ww][l15]);
  float lg = 0.f;
#pragma unroll
  for (int ww = 0; ww < 4; ++ww) lg += stat_l[ww][l15] * __expf(stat_m[ww][l15] - mg);
  const float scale = __expf(m - mg) / lg;
  const __fp16 hs = (__fp16)scale;
  const f16x4 sc4 = {hs, hs, hs, hs};

  // ---- Phase B: direct coalesced V fragment loads + attn via LDS bounce ----
  f32x4 oacc0 = {0.f, 0.f, 0.f, 0.f};
  f32x4 oacc1 = {0.f, 0.f, 0.f, 0.f};
  f32x4 oacc2 = {0.f, 0.f, 0.f, 0.f};
  f32x4 oacc3 = {0.f, 0.f, 0.f, 0.f};

  // V pipeline: 4 named sets x 4 db blocks
  f16x4 V0a, V0b, V0c, V0d, V1a, V1b, V1c, V1d;
  f16x4 V2a, V2b, V2c, V2d, V3a, V3b, V3c, V3d;

#define ISSUE_V(t, Va, Vb, Vc, Vd)                                           \
  Va = *(const f16x4*)(vfb + (size_t)(t) * 2048 + 0 * 512 + voff);           \
  Vb = *(const f16x4*)(vfb + (size_t)(t) * 2048 + 1 * 512 + voff);           \
  Vc = *(const f16x4*)(vfb + (size_t)(t) * 2048 + 2 * 512 + voff);           \
  Vd = *(const f16x4*)(vfb + (size_t)(t) * 2048 + 3 * 512 + voff);

#define BTILE(t, PH, Va, Vb, Vc, Vd)                                         \
  {                                                                          \
    const f16x4 pf = PH * sc4;                                               \
    f32x4 st;                                                                \
    st[0] = (float)pf[0]; st[1] = (float)pf[1];                              \
    st[2] = (float)pf[2]; st[3] = (float)pf[3];                              \
    *(f32x4*)(wb + l15 * 272 + ((t) & 3) * 64 + g * 16) = st;                \
    oacc0 = __builtin_amdgcn_mfma_f32_16x16x16f16(Va, pf, oacc0, 0, 0, 0);   \
    oacc1 = __builtin_amdgcn_mfma_f32_16x16x16f16(Vb, pf, oacc1, 0, 0, 0);   \
    oacc2 = __builtin_amdgcn_mfma_f32_16x16x16f16(Vc, pf, oacc2, 0, 0, 0);   \
    oacc3 = __builtin_amdgcn_mfma_f32_16x16x16f16(Vd, pf, oacc3, 0, 0, 0);   \
  }

#define STORE_A(c)                                                           \
  __builtin_nontemporal_store(                                               \
      *(const f32x4*)(wb + (0 * 4 + g) * 272 + l15 * 16),                    \
      (f32x4*)(abase + (size_t)(0 * 4 + g) * SEQ + (c) * 64 + l15 * 4));     \
  __builtin_nontemporal_store(                                               \
      *(const f32x4*)(wb + (1 * 4 + g) * 272 + l15 * 16),                    \
      (f32x4*)(abase + (size_t)(1 * 4 + g) * SEQ + (c) * 64 + l15 * 4));     \
  __builtin_nontemporal_store(                                               \
      *(const f32x4*)(wb + (2 * 4 + g) * 272 + l15 * 16),                    \
      (f32x4*)(abase + (size_t)(2 * 4 + g) * SEQ + (c) * 64 + l15 * 4));     \
  __builtin_nontemporal_store(                                               \
      *(const f32x4*)(wb + (3 * 4 + g) * 272 + l15 * 16),                    \
      (f32x4*)(abase + (size_t)(3 * 4 + g) * SEQ + (c) * 64 + l15 * 4));

#define BS(t, PH, Va, Vb, Vc, Vd)  BTILE(t, PH, Va, Vb, Vc, Vd) ISSUE_V((t) + 4, Va, Vb, Vc, Vd)
#define BSL(t, PH, Va, Vb, Vc, Vd) BTILE(t, PH, Va, Vb, Vc, Vd)

  ISSUE_V(0, V0a, V0b, V0c, V0d) ISSUE_V(1, V1a, V1b, V1c, V1d)
  ISSUE_V(2, V2a, V2b, V2c, V2d) ISSUE_V(3, V3a, V3b, V3c, V3d)

  BS(0, PH0, V0a, V0b, V0c, V0d)   BS(1, PH1, V1a, V1b, V1c, V1d)
  BS(2, PH2, V2a, V2b, V2c, V2d)   BS(3, PH3, V3a, V3b, V3c, V3d)   STORE_A(0)
  BS(4, PH4, V0a, V0b, V0c, V0d)   BS(5, PH5, V1a, V1b, V1c, V1d)
  BS(6, PH6, V2a, V2b, V2c, V2d)   BS(7, PH7, V3a, V3b, V3c, V3d)   STORE_A(1)
  BS(8, PH8, V0a, V0b, V0c, V0d)   BS(9, PH9, V1a, V1b, V1c, V1d)
  BS(10, PH10, V2a, V2b, V2c, V2d) BS(11, PH11, V3a, V3b, V3c, V3d) STORE_A(2)
  BS(12, PH12, V0a, V0b, V0c, V0d) BS(13, PH13, V1a, V1b, V1c, V1d)
  BS(14, PH14, V2a, V2b, V2c, V2d) BS(15, PH15, V3a, V3b, V3c, V3d) STORE_A(3)
  BS(16, PH16, V0a, V0b, V0c, V0d) BS(17, PH17, V1a, V1b, V1c, V1d)
  BS(18, PH18, V2a, V2b, V2c, V2d) BS(19, PH19, V3a, V3b, V3c, V3d) STORE_A(4)
  BS(20, PH20, V0a, V0b, V0c, V0d) BS(21, PH21, V1a, V1b, V1c, V1d)
  BS(22, PH22, V2a, V2b, V2c, V2d) BS(23, PH23, V3a, V3b, V3c, V3d) STORE_A(5)
  BS(24, PH24, V0a, V0b, V0c, V0d) BS(25, PH25, V1a, V1b, V1c, V1d)
  BS(26, PH26, V2a, V2b, V2c, V2d) BS(27, PH27, V3a, V3b, V3c, V3d) STORE_A(6)
  BSL(28, PH28, V0a, V0b, V0c, V0d) BSL(29, PH29, V1a, V1b, V1c, V1d)
  BSL(30, PH30, V2a, V2b, V2c, V2d) BSL(31, PH31, V3a, V3b, V3c, V3d) STORE_A(7)

#undef BS
#undef BSL
#undef BTILE
#undef ISSUE_V
#undef STORE_A

  // ---- cross-wave partial-O reduction (aliases the per-wave bounce buf) ----
  float* sred_w = (float*)pool[w];   // 1088 floats = 4352 B exactly
#pragma unroll
  for (int rr = 0; rr < 4; ++rr) {
    sred_w[(0 * 16 + g4 + rr) * 17 + l15] = oacc0[rr];
    sred_w[(1 * 16 + g4 + rr) * 17 + l15] = oacc1[rr];
    sred_w[(2 * 16 + g4 + rr) * 17 + l15] = oacc2[rr];
    sred_w[(3 * 16 + g4 + rr) * 17 + l15] = oacc3[rr];
  }
  __syncthreads();

#pragma unroll
  for (int ii = 0; ii < 4; ++ii) {
    const int i = tid + ii * 256;     // i in [0,1024): qq = i>>6, d = i&63
    const int qq = i >> 6;
    const int d = i & 63;
    const int o = d * 17 + qq;
    float s = ((const float*)pool[0])[o] + ((const float*)pool[1])[o] +
              ((const float*)pool[2])[o] + ((const float*)pool[3])[o];
    out[((size_t)(b * SEQ + q0 + qq)) * HD + d] = s;
  }
}

extern "C" void kernel_launch(void* const* d_in, const int* in_sizes, int n_in,
                              void* d_out, int out_size, void* d_ws, size_t ws_size,
                              hipStream_t stream) {
  const float* q    = (const float*)d_in[0];
  const float* k    = (const float*)d_in[1];
  const float* v    = (const float*)d_in[2];
  const float* mask = (const float*)d_in[3];

  float* out  = (float*)d_out;
  float* attn = out + (size_t)BATCH * SEQ * HD;  // tuple: (output, attn)

  const size_t nqk = (size_t)BATCH * SEQ * HD;
  __fp16* kfrag = (__fp16*)d_ws;
  __fp16* vfrag = kfrag + nqk;

  frag_kernel<<<dim3(2 * BATCH * 32), dim3(256), 0, stream>>>(k, v, kfrag, vfrag);
  attn_kernel<<<dim3(BATCH * (SEQ / 16)), dim3(256), 0, stream>>>(q, kfrag, vfrag, mask, out, attn);
}